// Round 1
// 688.674 us; speedup vs baseline: 1.0829x; 1.0829x over previous
//
#include <hip/hip_runtime.h>
#include <cfloat>
#include <math.h>

#define N_SAMP 32768
#define FF 8
#define HU 128
#define EE 1024
#define VV 2048
#define PP 320
#define SIGLEN 584
#define FINAL_W 9344

typedef unsigned short u16;
typedef unsigned int u32;
typedef short s16x8 __attribute__((ext_vector_type(8)));
typedef float f32x4 __attribute__((ext_vector_type(4)));

__device__ __forceinline__ u16 f2bf(float v) {
  u32 u = __float_as_uint(v);
  return (u16)((u + 0x7fffu + ((u >> 16) & 1u)) >> 16);
}
__device__ __forceinline__ float bf2f(u16 h) {
  return __uint_as_float(((u32)h) << 16);
}
// split v = hi + mid + lo (+ residual <= ~2^-25 |v|)
__device__ __forceinline__ void split3(float v, u16& h, u16& m, u16& l) {
  h = f2bf(v);
  float r = v - bf2f(h);
  m = f2bf(r);
  float r2 = r - bf2f(m);
  l = f2bf(r2);
}

__device__ __forceinline__ double wave_red(double v) {
#pragma unroll
  for (int off = 32; off > 0; off >>= 1) v += __shfl_xor(v, off, 64);
  return v;
}

// ---------------- prep: W limb-split + x partial stats + stats zeroing --------------
// blocks [0,1024): split W into 3 bf16 limb arrays
// blocks [1024,1056): 32 partial (sum, sumsq) of eigenvalues -> xp[64]
// blocks [1056,1072): zero stats1/stats2/stats3 (4112 doubles)
__global__ __launch_bounds__(256) void k_prep(const float* __restrict__ W,
                                              u16* __restrict__ Hh, u16* __restrict__ Hm,
                                              u16* __restrict__ Hl,
                                              const float* __restrict__ x,
                                              double* __restrict__ xp,
                                              double* __restrict__ stats_zero) {
  __shared__ double r1[4], r2[4];
  const int bid = blockIdx.x, tid = threadIdx.x;
  if (bid < 1024) {
    int i = bid * 256 + tid;
    u16 h, m, l;
    split3(W[i], h, m, l);
    Hh[i] = h; Hm[i] = m; Hl[i] = l;
  } else if (bid < 1056) {
    int b = bid - 1024;
    double s1 = 0.0, s2 = 0.0;
    int base = b * 1024 + tid;
#pragma unroll
    for (int r = 0; r < 4; ++r) {
      double v = (double)x[base + r * 256];
      s1 += v; s2 += v * v;
    }
    s1 = wave_red(s1); s2 = wave_red(s2);
    int wave = tid >> 6, lane = tid & 63;
    if (lane == 0) { r1[wave] = s1; r2[wave] = s2; }
    __syncthreads();
    if (tid == 0) {
      xp[b * 2 + 0] = r1[0] + r1[1] + r1[2] + r1[3];
      xp[b * 2 + 1] = r2[0] + r2[1] + r2[2] + r2[3];
    }
  } else {
    int q = (bid - 1056) * 256 + tid;
    stats_zero[q] = 0.0;
    if (bid == 1056 && tid < 16) stats_zero[4096 + tid] = 0.0;
  }
}

// ---------------- MFMA hidden-layer GEMM, bf16 3-split x 6 passes -------------------
// Yt[f][j][m] = sum_k A[m,k] W[j,k] + b[j]  (transposed out), plus column stats.
// MODE 0: A[m,k] = relu(x_m * p0_k + p1_k)   (folded input-layer BN; xp partials folded here)
// MODE 1: A[m,k] = relu(Yt_in[f][k][m] * sc_k + sh_k)  (sc/sh computed from stats_in here)
template<int MODE>
__global__ __launch_bounds__(256, 2)
void k_mgemm(const float* __restrict__ Ain,       // MODE0: x[N]; MODE1: Yt[F][HU][N]
             const double* __restrict__ xp,       // MODE0: 32 partial (s1,s2) pairs
             const float* __restrict__ w_in,      // MODE0: Win [F][HU]
             const float* __restrict__ g_in,
             const float* __restrict__ beta_in,
             const double* __restrict__ stats_in, // MODE1: [F*HU][2]
             const float* __restrict__ gM1,       // MODE1: gh base
             const float* __restrict__ betaM1,    // MODE1: betah base
             const u16* __restrict__ Wh_,         // [F][HU][HU] bf16 limbs (layer pre-offset)
             const u16* __restrict__ Wm_,
             const u16* __restrict__ Wl_,
             const float* __restrict__ bb, int bstride,
             float* __restrict__ Yt_out,
             double* __restrict__ stats) {
  // 6 staging buffers: rows of 32 k-limbs padded to 40 (80 B: 16-B aligned, 2-way banks)
  __shared__ u16 SB[6][128 * 40];
  __shared__ float p0[HU], p1[HU], biasl[HU], xl[HU];
  u16* Ah = SB[0]; u16* Am = SB[1]; u16* Al = SB[2];
  u16* Bh = SB[3]; u16* Bm = SB[4]; u16* Bl = SB[5];

  const int tid = threadIdx.x;
  const int f = blockIdx.y;
  const int m0 = blockIdx.x * 128;
  const int lane = tid & 63, ln = tid & 15, quad = (tid >> 4) & 3, wave = tid >> 6;

  if (tid < HU) {
    biasl[tid] = bb[(size_t)f * bstride + tid];
    if (MODE == 0) {
      double S1 = 0.0, S2 = 0.0;
#pragma unroll
      for (int r = 0; r < 32; ++r) { S1 += xp[r * 2]; S2 += xp[r * 2 + 1]; }
      double mx = S1 * (1.0 / 32768.0);
      double vx = S2 * (1.0 / 32768.0) - mx * mx;
      if (vx < 0) vx = 0;
      float w = w_in[f * HU + tid];
      double inv = 1.0 / sqrt((double)w * (double)w * vx + 1e-5);
      float sj = (float)inv * g_in[f * HU + tid] * w;
      p0[tid] = sj;
      p1[tid] = beta_in[f * HU + tid] - (float)mx * sj;
      xl[tid] = Ain[m0 + tid];
    } else {
      // former k_fin(stats1, gh, betah, 128, 256) inlined (identical double math)
      int idx = f * HU + tid;
      double S1 = stats_in[idx * 2 + 0], S2 = stats_in[idx * 2 + 1];
      double mean = S1 * (1.0 / 32768.0);
      double var = S2 * (1.0 / 32768.0) - mean * mean;
      if (var < 0) var = 0;
      double inv = 1.0 / sqrt(var + 1e-5);
      float gg = gM1[f * 256 + tid];
      float scv = (float)inv * gg;
      p0[tid] = scv;
      p1[tid] = betaM1[f * 256 + tid] - (float)mean * scv;
    }
  }

  f32x4 acc[2][8];
#pragma unroll
  for (int mt = 0; mt < 2; ++mt)
#pragma unroll
    for (int u = 0; u < 8; ++u) acc[mt][u] = (f32x4){0.f, 0.f, 0.f, 0.f};

  __syncthreads();

  for (int kk = 0; kk < 128; kk += 32) {
    // ---- stage A chunk [128 m][32 k] as 3 bf16 limbs, layout [m][k] ----
    if (MODE == 0) {
      const int m = tid >> 1, kh = (tid & 1) * 16;
      const float xv = xl[m];
      u32 ph[8], pm[8], pl[8];
#pragma unroll
      for (int jp = 0; jp < 8; ++jp) {
        u16 h0, m_0, l0, h1, m_1, l1;
        int k = kh + jp * 2;
        split3(fmaxf(fmaf(xv, p0[kk + k], p1[kk + k]), 0.f), h0, m_0, l0);
        split3(fmaxf(fmaf(xv, p0[kk + k + 1], p1[kk + k + 1]), 0.f), h1, m_1, l1);
        ph[jp] = (u32)h0 | ((u32)h1 << 16);
        pm[jp] = (u32)m_0 | ((u32)m_1 << 16);
        pl[jp] = (u32)l0 | ((u32)l1 << 16);
      }
      int off = m * 40 + kh;  // u16 index; byte = 80m + 2kh (32-B aligned)
      *(uint4*)&Ah[off] = make_uint4(ph[0], ph[1], ph[2], ph[3]);
      *(uint4*)&Ah[off + 8] = make_uint4(ph[4], ph[5], ph[6], ph[7]);
      *(uint4*)&Am[off] = make_uint4(pm[0], pm[1], pm[2], pm[3]);
      *(uint4*)&Am[off + 8] = make_uint4(pm[4], pm[5], pm[6], pm[7]);
      *(uint4*)&Al[off] = make_uint4(pl[0], pl[1], pl[2], pl[3]);
      *(uint4*)&Al[off + 8] = make_uint4(pl[4], pl[5], pl[6], pl[7]);
    } else {
#pragma unroll
      for (int r = 0; r < 4; ++r) {
        int flat = tid + r * 256;           // 0..1023
        int m = flat & 127, kq = flat >> 7; // kq 0..7 -> k = kq*4..+3
        const float* src = Ain + ((size_t)(f * HU + kk + kq * 4)) * N_SAMP + m0 + m;
        u32 ph[2], pm[2], pl[2];
#pragma unroll
        for (int ip = 0; ip < 2; ++ip) {
          int k = kq * 4 + ip * 2;
          float v0 = fmaxf(fmaf(src[(size_t)(ip * 2) * N_SAMP], p0[kk + k], p1[kk + k]), 0.f);
          float v1 = fmaxf(fmaf(src[(size_t)(ip * 2 + 1) * N_SAMP], p0[kk + k + 1], p1[kk + k + 1]), 0.f);
          u16 h0, m_0, l0, h1, m_1, l1;
          split3(v0, h0, m_0, l0);
          split3(v1, h1, m_1, l1);
          ph[ip] = (u32)h0 | ((u32)h1 << 16);
          pm[ip] = (u32)m_0 | ((u32)m_1 << 16);
          pl[ip] = (u32)l0 | ((u32)l1 << 16);
        }
        int off = m * 40 + kq * 4;  // byte = 80m + 8kq (8-B aligned)
        *(uint2*)&Ah[off] = make_uint2(ph[0], ph[1]);
        *(uint2*)&Am[off] = make_uint2(pm[0], pm[1]);
        *(uint2*)&Al[off] = make_uint2(pl[0], pl[1]);
      }
    }
    // ---- stage B chunk [128 n][32 k] from pre-split W limbs ----
#pragma unroll
    for (int r = 0; r < 2; ++r) {
      int flat = tid + r * 256;          // 0..511
      int n = flat >> 2, c = flat & 3;   // 16-B chunk c of the 64-B k-row piece
      size_t g = (size_t)f * (2 * HU * HU) + (size_t)n * HU + kk + c * 8;
      int off = n * 40 + c * 8;
      *(uint4*)&Bh[off] = *(const uint4*)&Wh_[g];
      *(uint4*)&Bm[off] = *(const uint4*)&Wm_[g];
      *(uint4*)&Bl[off] = *(const uint4*)&Wl_[g];
    }
    __syncthreads();
    // ---- MFMA: 2 m-tiles x 8 n-tiles x 6 limb passes ----
    s16x8 af0[3], af1[3];
    {
      int r0 = (wave * 32 + ln) * 40 + quad * 8;
      int r1 = (wave * 32 + 16 + ln) * 40 + quad * 8;
      af0[0] = *(const s16x8*)&Ah[r0]; af0[1] = *(const s16x8*)&Am[r0]; af0[2] = *(const s16x8*)&Al[r0];
      af1[0] = *(const s16x8*)&Ah[r1]; af1[1] = *(const s16x8*)&Am[r1]; af1[2] = *(const s16x8*)&Al[r1];
    }
#pragma unroll
    for (int u = 0; u < 8; ++u) {
      int bo = (u * 16 + ln) * 40 + quad * 8;
      s16x8 bh = *(const s16x8*)&Bh[bo];
      s16x8 bm = *(const s16x8*)&Bm[bo];
      s16x8 bl = *(const s16x8*)&Bl[bo];
      f32x4 a0 = acc[0][u], a1 = acc[1][u];
      a0 = __builtin_amdgcn_mfma_f32_16x16x32_bf16(af0[0], bh, a0, 0, 0, 0);
      a1 = __builtin_amdgcn_mfma_f32_16x16x32_bf16(af1[0], bh, a1, 0, 0, 0);
      a0 = __builtin_amdgcn_mfma_f32_16x16x32_bf16(af0[1], bh, a0, 0, 0, 0);
      a1 = __builtin_amdgcn_mfma_f32_16x16x32_bf16(af1[1], bh, a1, 0, 0, 0);
      a0 = __builtin_amdgcn_mfma_f32_16x16x32_bf16(af0[0], bm, a0, 0, 0, 0);
      a1 = __builtin_amdgcn_mfma_f32_16x16x32_bf16(af1[0], bm, a1, 0, 0, 0);
      a0 = __builtin_amdgcn_mfma_f32_16x16x32_bf16(af0[2], bh, a0, 0, 0, 0);
      a1 = __builtin_amdgcn_mfma_f32_16x16x32_bf16(af1[2], bh, a1, 0, 0, 0);
      a0 = __builtin_amdgcn_mfma_f32_16x16x32_bf16(af0[1], bm, a0, 0, 0, 0);
      a1 = __builtin_amdgcn_mfma_f32_16x16x32_bf16(af1[1], bm, a1, 0, 0, 0);
      a0 = __builtin_amdgcn_mfma_f32_16x16x32_bf16(af0[0], bl, a0, 0, 0, 0);
      a1 = __builtin_amdgcn_mfma_f32_16x16x32_bf16(af1[0], bl, a1, 0, 0, 0);
      acc[0][u] = a0; acc[1][u] = a1;
    }
    __syncthreads();
  }

  // ---- epilogue: bias, column stats, direct transposed float4 stores ----
  float cs1[8], cs2[8];
#pragma unroll
  for (int u = 0; u < 8; ++u) { cs1[u] = 0.f; cs2[u] = 0.f; }
#pragma unroll
  for (int u = 0; u < 8; ++u) {
    float b = biasl[u * 16 + ln];
#pragma unroll
    for (int mt = 0; mt < 2; ++mt) {
#pragma unroll
      for (int reg = 0; reg < 4; ++reg) {
        float v = acc[mt][u][reg] + b;
        acc[mt][u][reg] = v;
        cs1[u] += v;
        cs2[u] = fmaf(v, v, cs2[u]);
      }
      float4 st = make_float4(acc[mt][u][0], acc[mt][u][1], acc[mt][u][2], acc[mt][u][3]);
      *(float4*)&Yt_out[((size_t)(f * HU + u * 16 + ln)) * N_SAMP + m0 + wave * 32 + mt * 16 + quad * 4] = st;
    }
  }
  float* red1 = (float*)&SB[0][0];
  float* red2 = red1 + 2048;
  int wq = wave * 4 + quad;
#pragma unroll
  for (int u = 0; u < 8; ++u) {
    red1[wq * 128 + u * 16 + ln] = cs1[u];
    red2[wq * 128 + u * 16 + ln] = cs2[u];
  }
  __syncthreads();
  {
    int which = tid >> 7, n = tid & 127;
    const float* rp = which ? red2 : red1;
    float s = 0.f;
#pragma unroll
    for (int r = 0; r < 16; ++r) s += rp[r * 128 + n];
    atomicAdd(&stats[(f * HU + n) * 2 + which], (double)s);
  }
}

// ---------------- output layer (128 -> 1) + stats, reads TRANSPOSED Yt --------------
// BN params computed inline from stats2 (former k_fin(stats2, gh+128, betah+128, 128, 256))
__global__ __launch_bounds__(256, 4) void k_outlayer(const float* __restrict__ Yt,
                                                     const double* __restrict__ stats2,
                                                     const float* __restrict__ gh,
                                                     const float* __restrict__ betah,
                                                     const float* __restrict__ Wout,
                                                     const float* __restrict__ bout,
                                                     float* __restrict__ evs_pre,
                                                     double* __restrict__ stats3) {
  __shared__ float wj[HU], scl[HU], shl[HU];
  const int tid = threadIdx.x;
  const int f = blockIdx.y;
  const int i = blockIdx.x * 256 + tid;
  if (tid < HU) {
    wj[tid] = Wout[f * HU + tid];
    int idx = f * HU + tid;
    double S1 = stats2[idx * 2 + 0], S2 = stats2[idx * 2 + 1];
    double mean = S1 * (1.0 / 32768.0);
    double var = S2 * (1.0 / 32768.0) - mean * mean;
    if (var < 0) var = 0;
    double inv = 1.0 / sqrt(var + 1e-5);
    float gg = gh[128 + f * 256 + tid];
    float scv = (float)inv * gg;
    scl[tid] = scv;
    shl[tid] = betah[128 + f * 256 + tid] - (float)mean * scv;
  }
  __syncthreads();
  const float* base = Yt + (size_t)f * HU * N_SAMP + i;
  float acc = 0.f;
#pragma unroll
  for (int j = 0; j < HU; ++j) {
    float y = base[(size_t)j * N_SAMP];
    acc = fmaf(fmaxf(fmaf(y, scl[j], shl[j]), 0.f), wj[j], acc);
  }
  float yo = acc + bout[f];
  evs_pre[(size_t)f * N_SAMP + i] = yo;
  double v = (double)yo;
  double s1 = wave_red(v), s2 = wave_red(v * v);
  __shared__ double r1[4], r2[4];
  int wave = tid >> 6, lane = tid & 63;
  if (lane == 0) { r1[wave] = s1; r2[wave] = s2; }
  __syncthreads();
  if (tid == 0) atomicAdd(&stats3[f * 2 + 0], r1[0] + r1[1] + r1[2] + r1[3]);
  if (tid == 1) atomicAdd(&stats3[f * 2 + 1], r2[0] + r2[1] + r2[2] + r2[3]);
}

// ---------------- einsum lfv: fv[l,f,v] = sum_e evs[f,l,e] * eig[l,e,v] -------------
// sc3/sh3 computed inline from stats3 (former k_fin(stats3, gout, betaout, 1, 1, 8))
__global__ __launch_bounds__(256) void k_einsum(const float* __restrict__ evs_pre,
                                                const double* __restrict__ stats3,
                                                const float* __restrict__ gout,
                                                const float* __restrict__ betaout,
                                                const float* __restrict__ eig,
                                                float* __restrict__ fv) {
  __shared__ float ev[FF * EE];
  __shared__ float scl3[FF], shl3[FF];
  const int tid = threadIdx.x;
  const int l = blockIdx.y;
  const int v0 = blockIdx.x * 256;
  if (tid < FF) {
    double S1 = stats3[tid * 2 + 0], S2 = stats3[tid * 2 + 1];
    double mean = S1 * (1.0 / 32768.0);
    double var = S2 * (1.0 / 32768.0) - mean * mean;
    if (var < 0) var = 0;
    double inv = 1.0 / sqrt(var + 1e-5);
    float gg = gout[tid];
    float scv = (float)inv * gg;
    scl3[tid] = scv;
    shl3[tid] = betaout[tid] - (float)mean * scv;
  }
  __syncthreads();
#pragma unroll
  for (int r = 0; r < 32; ++r) {
    int q = tid + r * 256;
    int f = q >> 10, e = q & 1023;
    float y = evs_pre[(size_t)f * N_SAMP + l * EE + e];
    ev[q] = fmaxf(fmaf(y, scl3[f], shl3[f]), 0.f);
  }
  __syncthreads();
  const float* up = eig + (size_t)l * EE * VV + v0 + tid;
  float acc[8] = {0, 0, 0, 0, 0, 0, 0, 0};
  for (int e0 = 0; e0 < EE; e0 += 32) {
    float u[32];
#pragma unroll
    for (int t = 0; t < 32; ++t) u[t] = up[(size_t)(e0 + t) * VV];
#pragma unroll
    for (int t = 0; t < 32; ++t) {
#pragma unroll
      for (int f = 0; f < 8; ++f) acc[f] = fmaf(ev[f * EE + e0 + t], u[t], acc[f]);
    }
  }
#pragma unroll
  for (int f = 0; f < 8; ++f) fv[((size_t)(l * FF + f)) * VV + v0 + tid] = acc[f];
}

// ---------------- per-diagram: gather, project, sort, level-3 signature -------------
__global__ __launch_bounds__(256) void k_diagram(const float* __restrict__ fv,
                                                 const int* __restrict__ dgm0,
                                                 const int* __restrict__ dgm1rel,
                                                 const int* __restrict__ dgm1ext,
                                                 const float* __restrict__ Wp,
                                                 const float* __restrict__ bp,
                                                 float* __restrict__ xbuf) {
  __shared__ float vals[640];
  __shared__ float ps[7 * 512];
  __shared__ float dXl[320][8];
  const int tid = threadIdx.x;
  const int bid = blockIdx.x;
  const int row = bid >> 1;
  const int c = bid & 1;
  const float* fvr = fv + (size_t)row * VV;

  for (int k = tid; k < 640; k += 256) {
    int idx;
    if (c == 0) idx = (k < 512) ? dgm0[(size_t)row * 512 + k] : dgm1rel[(size_t)row * 129 + (640 - k)];
    else        idx = dgm1ext[(size_t)row * 640 + k];
    vals[k] = fvr[idx];
  }
  __syncthreads();
  for (int q = tid; q < 7 * 512; q += 256) {
    int s = q >> 9, p = q & 511;
    float pv = 3.402823466e+38f;
    if (p < PP) pv = fmaf(Wp[2 * s + 1], vals[2 * p + 1], fmaf(Wp[2 * s], vals[2 * p], bp[s]));
    ps[s * 512 + p] = pv;
  }
  for (int k = 2; k <= 512; k <<= 1) {
    for (int j = k >> 1; j > 0; j >>= 1) {
      __syncthreads();
      for (int q = tid; q < 1792; q += 256) {
        int s = q >> 8, ip = q & 255;
        int i = ((ip & ~(j - 1)) << 1) | (ip & (j - 1));
        int p2 = i | j;
        float a = ps[s * 512 + i], b = ps[s * 512 + p2];
        bool up = ((i & k) == 0);
        if ((a > b) == up) { ps[s * 512 + i] = b; ps[s * 512 + p2] = a; }
      }
    }
  }
  __syncthreads();
  for (int q = tid; q < 319 * 8; q += 256) {
    int p = q >> 3, d = q & 7;
    dXl[p][d] = (d == 0) ? (1.0f / 51360.0f)
                         : ps[(d - 1) * 512 + p + 1] - ps[(d - 1) * 512 + p];
  }
  __syncthreads();
  // signature: all 256 threads. thread = (a, b, dp): a=tid>>5, b=(tid>>2)&7, dp=tid&3.
  // s1a/s2r chains are replicated 4x per (a,b) (identical fma order as the 64-thread
  // version); each thread owns s3 components d = dp*2, dp*2+1 (same chains, same stores).
  {
    const int a = tid >> 5, b = (tid >> 2) & 7, dp = tid & 3;
    float s1a = 0.f, s2r = 0.f, s3r0 = 0.f, s3r1 = 0.f;
    for (int p = 0; p < 319; ++p) {
      float dxa = dXl[p][a];
      float dxb = dXl[p][b];
      float2 dd = *(const float2*)&dXl[p][dp * 2];
      float coefA = fmaf(dxa, (1.f / 3.f), s1a);
      float w = fmaf(0.5f * dxb, coefA, s2r);
      s2r = fmaf(dxb, fmaf(0.5f, dxa, s1a), s2r);
      s3r0 = fmaf(w, dd.x, s3r0);
      s3r1 = fmaf(w, dd.y, s3r1);
      s1a += dxa;
    }
    const int l = row >> 3, ff = row & 7;
    float* xr = xbuf + (size_t)l * FINAL_W + ff * (2 * SIGLEN) + c * SIGLEN;
    if (b == 0 && dp == 0) xr[a] = s1a;
    if (dp == 0) xr[8 + a * 8 + b] = s2r;
    float* s3p = xr + 72 + (a * 8 + b) * 8 + dp * 2;
    s3p[0] = s3r0;
    s3p[1] = s3r1;
  }
}

// ---------------- final 9344-dot per l (fp64) --------------------------------------
__global__ __launch_bounds__(256) void k_rowdot(const float* __restrict__ xbuf,
                                                const float* __restrict__ Wf,
                                                const float* __restrict__ bf,
                                                double* __restrict__ outpre) {
  const int tid = threadIdx.x, l = blockIdx.x;
  const float* xr = xbuf + (size_t)l * FINAL_W;
  double acc = 0.0;
  for (int k = tid; k < FINAL_W; k += 256) acc += (double)xr[k] * (double)Wf[k];
  acc = wave_red(acc);
  __shared__ double r[4];
  int wave = tid >> 6, lane = tid & 63;
  if (lane == 0) r[wave] = acc;
  __syncthreads();
  if (tid == 0) outpre[l] = r[0] + r[1] + r[2] + r[3] + (double)bf[0];
}

// ---------------- final BN over 32 samples (fp64, eps-dominated) --------------------
__global__ __launch_bounds__(64) void k_bnfin(const double* __restrict__ outpre,
                                              const float* __restrict__ g,
                                              const float* __restrict__ beta,
                                              float* __restrict__ dout) {
  int i = threadIdx.x;
  double v = (i < 32) ? outpre[i] : 0.0;
  double s1 = wave_red(v);
  double s2 = wave_red(v * v);
  double mean = s1 * (1.0 / 32.0);
  double var = s2 * (1.0 / 32.0) - mean * mean;
  if (var < 0) var = 0;
  double inv = 1.0 / sqrt(var + 1e-5);
  if (i < 32) dout[i] = (float)((v - mean) * inv * (double)g[0] + (double)beta[0]);
}

extern "C" void kernel_launch(void* const* d_in, const int* in_sizes, int n_in,
                              void* d_out, int out_size, void* d_ws, size_t ws_size,
                              hipStream_t stream) {
  const float* eig     = (const float*)d_in[0];
  const float* eigsq   = (const float*)d_in[1];
  const int*   dgm0    = (const int*)d_in[2];
  const int*   dgm1rel = (const int*)d_in[3];
  const int*   dgm1ext = (const int*)d_in[4];
  const float* Win     = (const float*)d_in[5];
  // d_in[6] = mlp_bin: cancels exactly in input-layer BN
  const float* gin     = (const float*)d_in[7];
  const float* betain  = (const float*)d_in[8];
  const float* Wh      = (const float*)d_in[9];
  const float* bh      = (const float*)d_in[10];
  const float* gh      = (const float*)d_in[11];
  const float* betah   = (const float*)d_in[12];
  const float* Wout    = (const float*)d_in[13];
  const float* bout    = (const float*)d_in[14];
  const float* gout    = (const float*)d_in[15];
  const float* betaout = (const float*)d_in[16];
  const float* Wp      = (const float*)d_in[17];
  const float* bp      = (const float*)d_in[18];
  const float* Wfin    = (const float*)d_in[19];
  const float* bfin    = (const float*)d_in[20];
  const float* gfin    = (const float*)d_in[21];
  const float* betafin = (const float*)d_in[22];

  char* ws = (char*)d_ws;
  float*  Yt      = (float*)(ws);                  // 134,217,728 B : [F][HU][N], in-place reuse
  float*  evs_pre = (float*)(ws + 134217728u);     //   1,048,576 B : [F][N]
  float*  fv      = (float*)(ws + 135266304u);     //   2,097,152 B : [L*F][V]
  float*  xbuf    = (float*)(ws + 137363456u);     //   1,196,032 B : [L][9344]
  double* stats1  = (double*)(ws + 138576384u);    // [F*HU][2]            (zeroed in k_prep)
  double* stats2  = stats1 + 2048;                 // [F*HU][2]            (zeroed in k_prep)
  double* stats3  = stats1 + 4096;                 // [F][2]               (zeroed in k_prep)
  double* xp      = stats1 + 4112;                 // [32][2] x partials   (written in k_prep)
  double* outpre  = stats1 + 4176;                 // [32]
  u16*    Whh     = (u16*)(ws + 138612736u);       // [F][2][HU][HU] bf16 limbs
  u16*    Whm     = (u16*)(ws + 139137024u);
  u16*    Whl     = (u16*)(ws + 139661312u);

  // prep: W limb-split (1024 blk) + x partial stats (32 blk) + zero stats (16 blk)
  k_prep<<<1072, 256, 0, stream>>>(Wh, Whh, Whm, Whl, eig, xp, stats1);
  // hidden layer 0 (A from scalar x; xp partials folded in prologue)
  k_mgemm<0><<<dim3(256, FF), 256, 0, stream>>>(eig, xp, Win, gin, betain,
                                                nullptr, nullptr, nullptr,
                                                Whh, Whm, Whl,
                                                bh, 256, Yt, stats1);
  // hidden layer 1 (in-place on Yt), sc1/sh1 from stats1 in prologue
  k_mgemm<1><<<dim3(256, FF), 256, 0, stream>>>(Yt, nullptr, nullptr, nullptr, nullptr,
                                                stats1, gh, betah,
                                                Whh + HU * HU, Whm + HU * HU, Whl + HU * HU,
                                                bh + 128, 256, Yt, stats2);
  // output layer, sc2/sh2 from stats2 in prologue
  k_outlayer<<<dim3(128, FF), 256, 0, stream>>>(Yt, stats2, gh, betah, Wout, bout,
                                                evs_pre, stats3);
  // einsum, sc3/sh3 from stats3 in prologue
  k_einsum<<<dim3(8, 32), 256, 0, stream>>>(evs_pre, stats3, gout, betaout, eigsq, fv);
  k_diagram<<<512, 256, 0, stream>>>(fv, dgm0, dgm1rel, dgm1ext, Wp, bp, xbuf);
  k_rowdot<<<32, 256, 0, stream>>>(xbuf, Wfin, bfin, outpre);
  k_bnfin<<<1, 64, 0, stream>>>(outpre, gfin, betafin, (float*)d_out);
}

// Round 3
// 663.932 us; speedup vs baseline: 1.1233x; 1.0373x over previous
//
#include <hip/hip_runtime.h>
#include <cfloat>
#include <math.h>

#define N_SAMP 32768
#define FF 8
#define HU 128
#define EE 1024
#define VV 2048
#define PP 320
#define SIGLEN 584
#define FINAL_W 9344

typedef unsigned short u16;
typedef unsigned int u32;
typedef short s16x8 __attribute__((ext_vector_type(8)));
typedef float f32x4 __attribute__((ext_vector_type(4)));

__device__ __forceinline__ u16 f2bf(float v) {
  u32 u = __float_as_uint(v);
  return (u16)((u + 0x7fffu + ((u >> 16) & 1u)) >> 16);
}
__device__ __forceinline__ float bf2f(u16 h) {
  return __uint_as_float(((u32)h) << 16);
}
// split v = hi + mid + lo (+ residual <= ~2^-25 |v|)
__device__ __forceinline__ void split3(float v, u16& h, u16& m, u16& l) {
  h = f2bf(v);
  float r = v - bf2f(h);
  m = f2bf(r);
  float r2 = r - bf2f(m);
  l = f2bf(r2);
}

__device__ __forceinline__ double wave_red(double v) {
#pragma unroll
  for (int off = 32; off > 0; off >>= 1) v += __shfl_xor(v, off, 64);
  return v;
}

// W limb arrays live in the EXACT LDS staging layout:
// [f*2+layer][chunk(4)][n(128)][40 u16]  (cols 0..31 = k data, 32..39 = pad, never read)
#define WPAD_ROW 40
#define WPAD_CHUNK (128 * WPAD_ROW)      // 5120 u16 per chunk
#define WPAD_LAYER (4 * WPAD_CHUNK)      // 20480 u16 per layer
#define WPAD_F (2 * WPAD_LAYER)          // 40960 u16 per f
#define WPAD_TOTAL (FF * WPAD_F)         // 327680 u16 per limb

// ---------------- prep: W limb-split (padded layout) + x partials + zeroing ---------
// blocks [0,1024): split W into 3 bf16 limb arrays (LDS-layout, padded)
// blocks [1024,1056): 32 partial (sum,sumsq) of eigenvalues -> D[0..63]
// blocks [1056,1073): zero D[64..4209) (stats1, stats2, stats3, outpre, counter)
__global__ __launch_bounds__(256) void k_prep(const float* __restrict__ W,
                                              u16* __restrict__ Hh, u16* __restrict__ Hm,
                                              u16* __restrict__ Hl,
                                              const float* __restrict__ x,
                                              double* __restrict__ D) {
  __shared__ double r1[4], r2[4];
  const int bid = blockIdx.x, tid = threadIdx.x;
  if (bid < 1024) {
    int i = bid * 256 + tid;                   // flat over [f2l][n][k]
    u16 h, m, l;
    split3(W[i], h, m, l);
    int k = i & 127, n = (i >> 7) & 127, f2l = i >> 14;
    int out = f2l * WPAD_LAYER + (k >> 5) * WPAD_CHUNK + n * WPAD_ROW + (k & 31);
    Hh[out] = h; Hm[out] = m; Hl[out] = l;
  } else if (bid < 1056) {
    int b = bid - 1024;
    double s1 = 0.0, s2 = 0.0;
    int base = b * 1024 + tid;
#pragma unroll
    for (int r = 0; r < 4; ++r) {
      double v = (double)x[base + r * 256];
      s1 += v; s2 += v * v;
    }
    s1 = wave_red(s1); s2 = wave_red(s2);
    int wave = tid >> 6, lane = tid & 63;
    if (lane == 0) { r1[wave] = s1; r2[wave] = s2; }
    __syncthreads();
    if (tid == 0) {
      D[b * 2 + 0] = r1[0] + r1[1] + r1[2] + r1[3];
      D[b * 2 + 1] = r2[0] + r2[1] + r2[2] + r2[3];
    }
  } else {
    int q = (bid - 1056) * 256 + tid;          // [0,4352)
    if (q < 4145) D[64 + q] = 0.0;             // stats1+stats2+stats3+outpre+cnt = 4145
  }
}

// ---------------- MFMA hidden-layer GEMM, bf16 3-split x 6 passes -------------------
// Yt[f][j][m] = sum_k A[m,k] W[j,k] + b[j]  (transposed out), plus column stats.
// MODE 0: A[m,k] = relu(x_m * p0_k + p1_k)   (folded input-layer BN; xp partials folded here)
// MODE 1: A[m,k] = relu(Yt_in[f][k][m] * sc_k + sh_k)  (sc/sh computed from stats_in here)
// B staged via async global_load_lds from the pre-padded limb arrays (issued before the
// A-side split3 compute so load latency hides under VALU work). LDS dest is wave-uniform
// (flat = wave + t*4), linear, 1024-B aligned; __syncthreads() drains vmcnt before MFMA.
template<int MODE>
__global__ __launch_bounds__(256, 2)
void k_mgemm(const float* __restrict__ Ain,       // MODE0: x[N]; MODE1: Yt[F][HU][N]
             const double* __restrict__ xp,       // MODE0: 32 partial (s1,s2) pairs
             const float* __restrict__ w_in,      // MODE0: Win [F][HU]
             const float* __restrict__ g_in,
             const float* __restrict__ beta_in,
             const double* __restrict__ stats_in, // MODE1: [F*HU][2]
             const float* __restrict__ gM1,       // MODE1: gh base
             const float* __restrict__ betaM1,    // MODE1: betah base
             const u16* __restrict__ Wh_,         // padded limbs, layer pre-offset
             const u16* __restrict__ Wm_,
             const u16* __restrict__ Wl_,
             const float* __restrict__ bb, int bstride,
             float* __restrict__ Yt_out,
             double* __restrict__ stats) {
  // 6 staging buffers: rows of 32 k-limbs padded to 40 (80 B: 16-B aligned, 2-way banks)
  __shared__ u16 SB[6][128 * 40];
  __shared__ float p0[HU], p1[HU], biasl[HU], xl[HU];
  u16* Ah = SB[0]; u16* Am = SB[1]; u16* Al = SB[2];
  u16* Bh = SB[3]; u16* Bm = SB[4]; u16* Bl = SB[5];

  const int tid = threadIdx.x;
  const int f = blockIdx.y;
  const int m0 = blockIdx.x * 128;
  const int lane = tid & 63, ln = tid & 15, quad = (tid >> 4) & 3, wave = tid >> 6;

  if (tid < HU) {
    biasl[tid] = bb[(size_t)f * bstride + tid];
    if (MODE == 0) {
      double S1 = 0.0, S2 = 0.0;
#pragma unroll
      for (int r = 0; r < 32; ++r) { S1 += xp[r * 2]; S2 += xp[r * 2 + 1]; }
      double mx = S1 * (1.0 / 32768.0);
      double vx = S2 * (1.0 / 32768.0) - mx * mx;
      if (vx < 0) vx = 0;
      float w = w_in[f * HU + tid];
      double inv = 1.0 / sqrt((double)w * (double)w * vx + 1e-5);
      float sj = (float)inv * g_in[f * HU + tid] * w;
      p0[tid] = sj;
      p1[tid] = beta_in[f * HU + tid] - (float)mx * sj;
      xl[tid] = Ain[m0 + tid];
    } else {
      // former k_fin(stats1, gh, betah, 128, 256) inlined (identical double math)
      int idx = f * HU + tid;
      double S1 = stats_in[idx * 2 + 0], S2 = stats_in[idx * 2 + 1];
      double mean = S1 * (1.0 / 32768.0);
      double var = S2 * (1.0 / 32768.0) - mean * mean;
      if (var < 0) var = 0;
      double inv = 1.0 / sqrt(var + 1e-5);
      float gg = gM1[f * 256 + tid];
      float scv = (float)inv * gg;
      p0[tid] = scv;
      p1[tid] = betaM1[f * 256 + tid] - (float)mean * scv;
    }
  }

  f32x4 acc[2][8];
#pragma unroll
  for (int mt = 0; mt < 2; ++mt)
#pragma unroll
    for (int u = 0; u < 8; ++u) acc[mt][u] = (f32x4){0.f, 0.f, 0.f, 0.f};

  __syncthreads();

  for (int kk = 0; kk < 128; kk += 32) {
    // ---- async stage B chunk: 3 limbs x 10240 B, LDS layout == global layout ----
    {
      const int chunk = kk >> 5;
      const u16* gH = Wh_ + (size_t)f * WPAD_F + chunk * WPAD_CHUNK;
      const u16* gM = Wm_ + (size_t)f * WPAD_F + chunk * WPAD_CHUNK;
      const u16* gL = Wl_ + (size_t)f * WPAD_F + chunk * WPAD_CHUNK;
#pragma unroll
      for (int t = 0; t < 8; ++t) {
        int flat = wave + t * 4;            // wave-uniform; 30 real issues of 1024 B
        if (flat < 30) {
          int L = (flat >= 20) ? 2 : (flat >= 10 ? 1 : 0);
          int p = flat - L * 10;
          const u16* g = (L == 0 ? gH : (L == 1 ? gM : gL)) + p * 512 + lane * 8;
          u16* d = (L == 0 ? Bh : (L == 1 ? Bm : Bl)) + p * 512;
          __builtin_amdgcn_global_load_lds(
              (const __attribute__((address_space(1))) void*)g,
              (__attribute__((address_space(3))) void*)d, 16, 0, 0);
        }
      }
    }
    // ---- stage A chunk [128 m][32 k] as 3 bf16 limbs, layout [m][k] ----
    if (MODE == 0) {
      const int m = tid >> 1, kh = (tid & 1) * 16;
      const float xv = xl[m];
      u32 ph[8], pm[8], pl[8];
#pragma unroll
      for (int jp = 0; jp < 8; ++jp) {
        u16 h0, m_0, l0, h1, m_1, l1;
        int k = kh + jp * 2;
        split3(fmaxf(fmaf(xv, p0[kk + k], p1[kk + k]), 0.f), h0, m_0, l0);
        split3(fmaxf(fmaf(xv, p0[kk + k + 1], p1[kk + k + 1]), 0.f), h1, m_1, l1);
        ph[jp] = (u32)h0 | ((u32)h1 << 16);
        pm[jp] = (u32)m_0 | ((u32)m_1 << 16);
        pl[jp] = (u32)l0 | ((u32)l1 << 16);
      }
      int off = m * 40 + kh;  // u16 index; byte = 80m + 2kh (32-B aligned)
      *(uint4*)&Ah[off] = make_uint4(ph[0], ph[1], ph[2], ph[3]);
      *(uint4*)&Ah[off + 8] = make_uint4(ph[4], ph[5], ph[6], ph[7]);
      *(uint4*)&Am[off] = make_uint4(pm[0], pm[1], pm[2], pm[3]);
      *(uint4*)&Am[off + 8] = make_uint4(pm[4], pm[5], pm[6], pm[7]);
      *(uint4*)&Al[off] = make_uint4(pl[0], pl[1], pl[2], pl[3]);
      *(uint4*)&Al[off + 8] = make_uint4(pl[4], pl[5], pl[6], pl[7]);
    } else {
#pragma unroll
      for (int r = 0; r < 4; ++r) {
        int flat = tid + r * 256;           // 0..1023
        int m = flat & 127, kq = flat >> 7; // kq 0..7 -> k = kq*4..+3
        const float* src = Ain + ((size_t)(f * HU + kk + kq * 4)) * N_SAMP + m0 + m;
        u32 ph[2], pm[2], pl[2];
#pragma unroll
        for (int ip = 0; ip < 2; ++ip) {
          int k = kq * 4 + ip * 2;
          float v0 = fmaxf(fmaf(src[(size_t)(ip * 2) * N_SAMP], p0[kk + k], p1[kk + k]), 0.f);
          float v1 = fmaxf(fmaf(src[(size_t)(ip * 2 + 1) * N_SAMP], p0[kk + k + 1], p1[kk + k + 1]), 0.f);
          u16 h0, m_0, l0, h1, m_1, l1;
          split3(v0, h0, m_0, l0);
          split3(v1, h1, m_1, l1);
          ph[ip] = (u32)h0 | ((u32)h1 << 16);
          pm[ip] = (u32)m_0 | ((u32)m_1 << 16);
          pl[ip] = (u32)l0 | ((u32)l1 << 16);
        }
        int off = m * 40 + kq * 4;  // byte = 80m + 8kq (8-B aligned)
        *(uint2*)&Ah[off] = make_uint2(ph[0], ph[1]);
        *(uint2*)&Am[off] = make_uint2(pm[0], pm[1]);
        *(uint2*)&Al[off] = make_uint2(pl[0], pl[1]);
      }
    }
    __syncthreads();   // compiler emits s_waitcnt vmcnt(0) lgkmcnt(0) before s_barrier
    // ---- MFMA: 2 m-tiles x 8 n-tiles x 6 limb passes ----
    s16x8 af0[3], af1[3];
    {
      int r0 = (wave * 32 + ln) * 40 + quad * 8;
      int r1 = (wave * 32 + 16 + ln) * 40 + quad * 8;
      af0[0] = *(const s16x8*)&Ah[r0]; af0[1] = *(const s16x8*)&Am[r0]; af0[2] = *(const s16x8*)&Al[r0];
      af1[0] = *(const s16x8*)&Ah[r1]; af1[1] = *(const s16x8*)&Am[r1]; af1[2] = *(const s16x8*)&Al[r1];
    }
#pragma unroll
    for (int u = 0; u < 8; ++u) {
      int bo = (u * 16 + ln) * 40 + quad * 8;
      s16x8 bh = *(const s16x8*)&Bh[bo];
      s16x8 bm = *(const s16x8*)&Bm[bo];
      s16x8 bl = *(const s16x8*)&Bl[bo];
      f32x4 a0 = acc[0][u], a1 = acc[1][u];
      a0 = __builtin_amdgcn_mfma_f32_16x16x32_bf16(af0[0], bh, a0, 0, 0, 0);
      a1 = __builtin_amdgcn_mfma_f32_16x16x32_bf16(af1[0], bh, a1, 0, 0, 0);
      a0 = __builtin_amdgcn_mfma_f32_16x16x32_bf16(af0[1], bh, a0, 0, 0, 0);
      a1 = __builtin_amdgcn_mfma_f32_16x16x32_bf16(af1[1], bh, a1, 0, 0, 0);
      a0 = __builtin_amdgcn_mfma_f32_16x16x32_bf16(af0[0], bm, a0, 0, 0, 0);
      a1 = __builtin_amdgcn_mfma_f32_16x16x32_bf16(af1[0], bm, a1, 0, 0, 0);
      a0 = __builtin_amdgcn_mfma_f32_16x16x32_bf16(af0[2], bh, a0, 0, 0, 0);
      a1 = __builtin_amdgcn_mfma_f32_16x16x32_bf16(af1[2], bh, a1, 0, 0, 0);
      a0 = __builtin_amdgcn_mfma_f32_16x16x32_bf16(af0[1], bm, a0, 0, 0, 0);
      a1 = __builtin_amdgcn_mfma_f32_16x16x32_bf16(af1[1], bm, a1, 0, 0, 0);
      a0 = __builtin_amdgcn_mfma_f32_16x16x32_bf16(af0[0], bl, a0, 0, 0, 0);
      a1 = __builtin_amdgcn_mfma_f32_16x16x32_bf16(af1[0], bl, a1, 0, 0, 0);
      acc[0][u] = a0; acc[1][u] = a1;
    }
    __syncthreads();
  }

  // ---- epilogue: bias, column stats, direct transposed float4 stores ----
  float cs1[8], cs2[8];
#pragma unroll
  for (int u = 0; u < 8; ++u) { cs1[u] = 0.f; cs2[u] = 0.f; }
#pragma unroll
  for (int u = 0; u < 8; ++u) {
    float b = biasl[u * 16 + ln];
#pragma unroll
    for (int mt = 0; mt < 2; ++mt) {
#pragma unroll
      for (int reg = 0; reg < 4; ++reg) {
        float v = acc[mt][u][reg] + b;
        acc[mt][u][reg] = v;
        cs1[u] += v;
        cs2[u] = fmaf(v, v, cs2[u]);
      }
      float4 st = make_float4(acc[mt][u][0], acc[mt][u][1], acc[mt][u][2], acc[mt][u][3]);
      *(float4*)&Yt_out[((size_t)(f * HU + u * 16 + ln)) * N_SAMP + m0 + wave * 32 + mt * 16 + quad * 4] = st;
    }
  }
  float* red1 = (float*)&SB[0][0];
  float* red2 = red1 + 2048;
  int wq = wave * 4 + quad;
#pragma unroll
  for (int u = 0; u < 8; ++u) {
    red1[wq * 128 + u * 16 + ln] = cs1[u];
    red2[wq * 128 + u * 16 + ln] = cs2[u];
  }
  __syncthreads();
  {
    int which = tid >> 7, n = tid & 127;
    const float* rp = which ? red2 : red1;
    float s = 0.f;
#pragma unroll
    for (int r = 0; r < 16; ++r) s += rp[r * 128 + n];
    atomicAdd(&stats[(f * HU + n) * 2 + which], (double)s);
  }
}

// ---------------- output layer (128 -> 1) + stats, reads TRANSPOSED Yt --------------
// BN params computed inline from stats2; float2-vectorized sample loads.
__global__ __launch_bounds__(256, 4) void k_outlayer(const float* __restrict__ Yt,
                                                     const double* __restrict__ stats2,
                                                     const float* __restrict__ gh,
                                                     const float* __restrict__ betah,
                                                     const float* __restrict__ Wout,
                                                     const float* __restrict__ bout,
                                                     float* __restrict__ evs_pre,
                                                     double* __restrict__ stats3) {
  __shared__ float wj[HU], scl[HU], shl[HU];
  const int tid = threadIdx.x;
  const int f = blockIdx.y;
  const int i = (blockIdx.x * 256 + tid) * 2;
  if (tid < HU) {
    wj[tid] = Wout[f * HU + tid];
    int idx = f * HU + tid;
    double S1 = stats2[idx * 2 + 0], S2 = stats2[idx * 2 + 1];
    double mean = S1 * (1.0 / 32768.0);
    double var = S2 * (1.0 / 32768.0) - mean * mean;
    if (var < 0) var = 0;
    double inv = 1.0 / sqrt(var + 1e-5);
    float gg = gh[128 + f * 256 + tid];
    float scv = (float)inv * gg;
    scl[tid] = scv;
    shl[tid] = betah[128 + f * 256 + tid] - (float)mean * scv;
  }
  __syncthreads();
  const float2* base2 = (const float2*)(Yt + (size_t)f * HU * N_SAMP + i);
  float a0 = 0.f, a1 = 0.f;
#pragma unroll
  for (int j = 0; j < HU; ++j) {
    float2 y = base2[(size_t)j * (N_SAMP / 2)];
    a0 = fmaf(fmaxf(fmaf(y.x, scl[j], shl[j]), 0.f), wj[j], a0);
    a1 = fmaf(fmaxf(fmaf(y.y, scl[j], shl[j]), 0.f), wj[j], a1);
  }
  float yo0 = a0 + bout[f];
  float yo1 = a1 + bout[f];
  *(float2*)&evs_pre[(size_t)f * N_SAMP + i] = make_float2(yo0, yo1);
  double v0 = (double)yo0, v1 = (double)yo1;
  double s1 = wave_red(v0 + v1), s2 = wave_red(v0 * v0 + v1 * v1);
  __shared__ double r1[4], r2[4];
  int wave = tid >> 6, lane = tid & 63;
  if (lane == 0) { r1[wave] = s1; r2[wave] = s2; }
  __syncthreads();
  if (tid == 0) atomicAdd(&stats3[f * 2 + 0], r1[0] + r1[1] + r1[2] + r1[3]);
  if (tid == 1) atomicAdd(&stats3[f * 2 + 1], r2[0] + r2[1] + r2[2] + r2[3]);
}

// ---------------- einsum lfv: fv[l,f,v] = sum_e evs[f,l,e] * eig[l,e,v] -------------
__global__ __launch_bounds__(256) void k_einsum(const float* __restrict__ evs_pre,
                                                const double* __restrict__ stats3,
                                                const float* __restrict__ gout,
                                                const float* __restrict__ betaout,
                                                const float* __restrict__ eig,
                                                float* __restrict__ fv) {
  __shared__ __align__(16) float ev[FF * EE];
  __shared__ float scl3[FF], shl3[FF];
  const int tid = threadIdx.x;
  const int l = blockIdx.y;
  const int v0 = blockIdx.x * 256;
  if (tid < FF) {
    double S1 = stats3[tid * 2 + 0], S2 = stats3[tid * 2 + 1];
    double mean = S1 * (1.0 / 32768.0);
    double var = S2 * (1.0 / 32768.0) - mean * mean;
    if (var < 0) var = 0;
    double inv = 1.0 / sqrt(var + 1e-5);
    float gg = gout[tid];
    float scv = (float)inv * gg;
    scl3[tid] = scv;
    shl3[tid] = betaout[tid] - (float)mean * scv;
  }
  __syncthreads();
#pragma unroll
  for (int r = 0; r < 8; ++r) {
    int flat = tid + r * 256;          // 0..2047 float4 chunks
    int fch = flat >> 8, e4 = (flat & 255) * 4;
    float4 y = *(const float4*)&evs_pre[(size_t)fch * N_SAMP + l * EE + e4];
    float sv = scl3[fch], hv = shl3[fch];
    float* evp = &ev[fch * EE + e4];
    evp[0] = fmaxf(fmaf(y.x, sv, hv), 0.f);
    evp[1] = fmaxf(fmaf(y.y, sv, hv), 0.f);
    evp[2] = fmaxf(fmaf(y.z, sv, hv), 0.f);
    evp[3] = fmaxf(fmaf(y.w, sv, hv), 0.f);
  }
  __syncthreads();
  const float* up = eig + (size_t)l * EE * VV + v0 + tid;
  float acc[8] = {0, 0, 0, 0, 0, 0, 0, 0};
  for (int e0 = 0; e0 < EE; e0 += 32) {
    float u[32];
#pragma unroll
    for (int t = 0; t < 32; ++t) u[t] = up[(size_t)(e0 + t) * VV];
#pragma unroll
    for (int t = 0; t < 32; ++t) {
#pragma unroll
      for (int f = 0; f < 8; ++f) acc[f] = fmaf(ev[f * EE + e0 + t], u[t], acc[f]);
    }
  }
#pragma unroll
  for (int f = 0; f < 8; ++f) fv[((size_t)(l * FF + f)) * VV + v0 + tid] = acc[f];
}

// ---------------- per-diagram: gather, project, sort, sig3, fused final dot ---------
// Each block dots its 584 signature values with W_fin in f64 and atomically adds to
// outpre[l]; the last of the 512 blocks (device-scope counter) runs the final BN.
// No spin-waits anywhere: worst case under a fence bug is wrong output, never a hang.
__global__ __launch_bounds__(256) void k_diagram(const float* __restrict__ fv,
                                                 const int* __restrict__ dgm0,
                                                 const int* __restrict__ dgm1rel,
                                                 const int* __restrict__ dgm1ext,
                                                 const float* __restrict__ Wp,
                                                 const float* __restrict__ bp,
                                                 const float* __restrict__ Wf,
                                                 const float* __restrict__ bf,
                                                 const float* __restrict__ gfin,
                                                 const float* __restrict__ betafin,
                                                 double* __restrict__ outpre,
                                                 unsigned int* __restrict__ cnt,
                                                 float* __restrict__ dout) {
  __shared__ float vals[640];
  __shared__ float ps[7 * 512];
  __shared__ float dXl[320][8];
  __shared__ double rr[4];
  __shared__ unsigned int lastFlag;
  const int tid = threadIdx.x;
  const int bid = blockIdx.x;
  const int row = bid >> 1;
  const int c = bid & 1;
  const float* fvr = fv + (size_t)row * VV;

  for (int k = tid; k < 640; k += 256) {
    int idx;
    if (c == 0) idx = (k < 512) ? dgm0[(size_t)row * 512 + k] : dgm1rel[(size_t)row * 129 + (640 - k)];
    else        idx = dgm1ext[(size_t)row * 640 + k];
    vals[k] = fvr[idx];
  }
  __syncthreads();
  for (int q = tid; q < 7 * 512; q += 256) {
    int s = q >> 9, p = q & 511;
    float pv = 3.402823466e+38f;
    if (p < PP) pv = fmaf(Wp[2 * s + 1], vals[2 * p + 1], fmaf(Wp[2 * s], vals[2 * p], bp[s]));
    ps[s * 512 + p] = pv;
  }
  for (int k = 2; k <= 512; k <<= 1) {
    for (int j = k >> 1; j > 0; j >>= 1) {
      __syncthreads();
      for (int q = tid; q < 1792; q += 256) {
        int s = q >> 8, ip = q & 255;
        int i = ((ip & ~(j - 1)) << 1) | (ip & (j - 1));
        int p2 = i | j;
        float a = ps[s * 512 + i], b = ps[s * 512 + p2];
        bool up = ((i & k) == 0);
        if ((a > b) == up) { ps[s * 512 + i] = b; ps[s * 512 + p2] = a; }
      }
    }
  }
  __syncthreads();
  for (int q = tid; q < 319 * 8; q += 256) {
    int p = q >> 3, d = q & 7;
    dXl[p][d] = (d == 0) ? (1.0f / 51360.0f)
                         : ps[(d - 1) * 512 + p + 1] - ps[(d - 1) * 512 + p];
  }
  __syncthreads();
  // signature: all 256 threads. thread = (a, b, dp): a=tid>>5, b=(tid>>2)&7, dp=tid&3.
  // s1a/s2r chains replicated (identical fma order); each thread owns s3 d = dp*2, dp*2+1.
  {
    const int a = tid >> 5, b = (tid >> 2) & 7, dp = tid & 3;
    float s1a = 0.f, s2r = 0.f, s3r0 = 0.f, s3r1 = 0.f;
    for (int p = 0; p < 319; ++p) {
      float dxa = dXl[p][a];
      float dxb = dXl[p][b];
      float2 dd = *(const float2*)&dXl[p][dp * 2];
      float coefA = fmaf(dxa, (1.f / 3.f), s1a);
      float w = fmaf(0.5f * dxb, coefA, s2r);
      s2r = fmaf(dxb, fmaf(0.5f, dxa, s1a), s2r);
      s3r0 = fmaf(w, dd.x, s3r0);
      s3r1 = fmaf(w, dd.y, s3r1);
      s1a += dxa;
    }
    const int l = row >> 3, ff = row & 7;
    const int base = ff * (2 * SIGLEN) + c * SIGLEN;
    // fused W_fin dot: each product (double)sig_val * (double)Wf[k] identical to the
    // former k_rowdot; only the f64 summation order differs (below f32 rounding).
    double part = (double)s3r0 * (double)Wf[base + 72 + (a * 8 + b) * 8 + dp * 2]
                + (double)s3r1 * (double)Wf[base + 72 + (a * 8 + b) * 8 + dp * 2 + 1];
    if (dp == 0) part += (double)s2r * (double)Wf[base + 8 + a * 8 + b];
    if (b == 0 && dp == 0) part += (double)s1a * (double)Wf[base + a];
    part = wave_red(part);
    int wv = tid >> 6, lnn = tid & 63;
    if (lnn == 0) rr[wv] = part;
    __syncthreads();
    if (tid == 0) {
      atomicAdd(&outpre[l], rr[0] + rr[1] + rr[2] + rr[3]);
      __threadfence();
      unsigned int old = atomicAdd(cnt, 1u);
      lastFlag = (old == 511u) ? 1u : 0u;
    }
    __syncthreads();
    if (lastFlag && tid < 64) {
      __threadfence();
      double v = 0.0;
      if (tid < 32) v = ((volatile double*)outpre)[tid] + (double)bf[0];
      double s1 = wave_red(v);
      double s2 = wave_red(v * v);
      double mean = s1 * (1.0 / 32.0);
      double var = s2 * (1.0 / 32.0) - mean * mean;
      if (var < 0) var = 0;
      double inv = 1.0 / sqrt(var + 1e-5);
      if (tid < 32) dout[tid] = (float)((v - mean) * inv * (double)gfin[0] + (double)betafin[0]);
    }
  }
}

extern "C" void kernel_launch(void* const* d_in, const int* in_sizes, int n_in,
                              void* d_out, int out_size, void* d_ws, size_t ws_size,
                              hipStream_t stream) {
  const float* eig     = (const float*)d_in[0];
  const float* eigsq   = (const float*)d_in[1];
  const int*   dgm0    = (const int*)d_in[2];
  const int*   dgm1rel = (const int*)d_in[3];
  const int*   dgm1ext = (const int*)d_in[4];
  const float* Win     = (const float*)d_in[5];
  // d_in[6] = mlp_bin: cancels exactly in input-layer BN
  const float* gin     = (const float*)d_in[7];
  const float* betain  = (const float*)d_in[8];
  const float* Wh      = (const float*)d_in[9];
  const float* bh      = (const float*)d_in[10];
  const float* gh      = (const float*)d_in[11];
  const float* betah   = (const float*)d_in[12];
  const float* Wout    = (const float*)d_in[13];
  const float* bout    = (const float*)d_in[14];
  const float* gout    = (const float*)d_in[15];
  const float* betaout = (const float*)d_in[16];
  const float* Wp      = (const float*)d_in[17];
  const float* bp      = (const float*)d_in[18];
  const float* Wfin    = (const float*)d_in[19];
  const float* bfin    = (const float*)d_in[20];
  const float* gfin    = (const float*)d_in[21];
  const float* betafin = (const float*)d_in[22];

  char* ws = (char*)d_ws;
  float*  Yt      = (float*)(ws);                  // 134,217,728 B : [F][HU][N], in-place reuse
  float*  evs_pre = (float*)(ws + 134217728u);     //   1,048,576 B : [F][N]
  float*  fv      = (float*)(ws + 135266304u);     //   2,097,152 B : [L*F][V]
  // f64 scratch region D: [0..63] xp, [64..2111] stats1, [2112..4159] stats2,
  // [4160..4175] stats3, [4176..4207] outpre, [4208] counter. Zeroed range [64,4209).
  double* D       = (double*)(ws + 138576384u);
  double* xp      = D;
  double* stats1  = D + 64;
  double* stats2  = D + 2112;
  double* stats3  = D + 4160;
  double* outpre  = D + 4176;
  unsigned int* cnt = (unsigned int*)(D + 4208);
  u16*    Whh     = (u16*)(ws + 138612736u);       // padded limbs, 655,360 B each
  u16*    Whm     = Whh + WPAD_TOTAL;
  u16*    Whl     = Whm + WPAD_TOTAL;

  // prep: W limb-split padded (1024 blk) + x partials (32 blk) + zero D (17 blk)
  k_prep<<<1073, 256, 0, stream>>>(Wh, Whh, Whm, Whl, eig, D);
  // hidden layer 0 (A from scalar x; xp partials folded in prologue)
  k_mgemm<0><<<dim3(256, FF), 256, 0, stream>>>(eig, xp, Win, gin, betain,
                                                nullptr, nullptr, nullptr,
                                                Whh, Whm, Whl,
                                                bh, 256, Yt, stats1);
  // hidden layer 1 (in-place on Yt), sc1/sh1 from stats1 in prologue
  k_mgemm<1><<<dim3(256, FF), 256, 0, stream>>>(Yt, nullptr, nullptr, nullptr, nullptr,
                                                stats1, gh, betah,
                                                Whh + WPAD_LAYER, Whm + WPAD_LAYER, Whl + WPAD_LAYER,
                                                bh + 128, 256, Yt, stats2);
  // output layer, sc2/sh2 from stats2 in prologue (float2 loads)
  k_outlayer<<<dim3(64, FF), 256, 0, stream>>>(Yt, stats2, gh, betah, Wout, bout,
                                               evs_pre, stats3);
  // einsum, sc3/sh3 from stats3 in prologue
  k_einsum<<<dim3(8, 32), 256, 0, stream>>>(evs_pre, stats3, gout, betaout, eigsq, fv);
  // diagram + fused final dot + last-block BN
  k_diagram<<<512, 256, 0, stream>>>(fv, dgm0, dgm1rel, dgm1ext, Wp, bp,
                                     Wfin, bfin, gfin, betafin, outpre, cnt,
                                     (float*)d_out);
}